// Round 15
// baseline (510.803 us; speedup 1.0000x reference)
//
#include <hip/hip_runtime.h>
#include <math.h>

#define DEVI __device__ __forceinline__

namespace {

constexpr int N_  = 2048;
constexpr int E_  = 32768;
constexpr int E2_ = 65536;
constexpr int M_  = 64000;   // 8 * 20^3
constexpr int NT_ = 2048;    // radial table resolution
constexpr float TMAX_ = 5.5f;
constexpr float TH_ = TMAX_ / NT_;

using bf16x8 = __attribute__((ext_vector_type(8))) short;
using f32x4  = __attribute__((ext_vector_type(4))) float;

DEVI float sigm(float x)  { return 1.0f/(1.0f+expf(-x)); }
DEVI float geluf(float x) {
  float t = tanhf(0.7978845608028654f*(x + 0.044715f*x*x*x));
  return 0.5f*x*(1.0f+t);
}

DEVI unsigned short bf16rn(float x){
  unsigned u = __float_as_uint(x);
  unsigned r = u + 0x7FFFu + ((u>>16)&1u);
  return (unsigned short)(r>>16);
}
DEVI void bf16split(float x, unsigned short& h, unsigned short& l){
  h = bf16rn(x);
  float hf = __uint_as_float(((unsigned)h)<<16);
  l = bf16rn(x - hf);
}

// ---------------- utility ----------------
__global__ void zero3_k(float* __restrict__ out, float* __restrict__ af,
                        float* __restrict__ mf){
  int i = blockIdx.x*256 + threadIdx.x;
  if (i < 8) out[i] = 0.0f;
  if (i < N_) af[i] = 0.0f;
  if (i < M_*32) mf[i] = 0.0f;
}

__global__ void meshpos_k(const float* __restrict__ cell, float* __restrict__ mp){
  int m = blockIdx.x*256 + threadIdx.x;
  if (m >= M_) return;
  int b = m/8000, r = m%8000;
  float fx = (float)(r/400)    * 0.05f;
  float fy = (float)((r/20)%20)* 0.05f;
  float fz = (float)(r%20)     * 0.05f;
  const float* c = cell + b*9;
  mp[(size_t)m*3+0] = fx*c[0] + fy*c[3] + fz*c[6];
  mp[(size_t)m*3+1] = fx*c[1] + fy*c[4] + fz*c[7];
  mp[(size_t)m*3+2] = fx*c[2] + fy*c[5] + fz*c[8];
}

DEVI void edge_core(float ex, float ey, float ez, float* s, float* el_out, int e){
  float el = sqrtf(ex*ex+ey*ey+ez*ez) + 1e-8f;
  el_out[e] = el;
  float x = ex/el, y = ey/el, z = ez/el;
  float* sp = s + (size_t)e*9;
  sp[0] = 0.28209479177387814f;
  sp[1] = 0.4886025119029199f*y;
  sp[2] = 0.4886025119029199f*z;
  sp[3] = 0.4886025119029199f*x;
  sp[4] = 1.0925484305920792f*x*y;
  sp[5] = 1.0925484305920792f*y*z;
  sp[6] = 0.31539156525252005f*(3.0f*z*z-1.0f);
  sp[7] = 1.0925484305920792f*x*z;
  sp[8] = 0.5462742152960396f*(x*x-y*y);
}

__global__ void edge_both_k(const float* __restrict__ pos, const float* __restrict__ meshpos,
                            const int* __restrict__ esrc, const int* __restrict__ edst,
                            const int* __restrict__ asrc, const int* __restrict__ mdst,
                            float* __restrict__ she, float* __restrict__ ELe,
                            float* __restrict__ sh2, float* __restrict__ EL2){
  int e = blockIdx.x*256 + threadIdx.x;
  if (e < E_){
    int a = esrc[e], b = edst[e];
    edge_core(pos[(size_t)a*3+0]-pos[(size_t)b*3+0],
              pos[(size_t)a*3+1]-pos[(size_t)b*3+1],
              pos[(size_t)a*3+2]-pos[(size_t)b*3+2], she, ELe, e);
  } else if (e < E_ + E2_){
    int e2 = e - E_;
    int a = mdst[e2], b = asrc[e2];
    edge_core(meshpos[(size_t)a*3+0]-pos[(size_t)b*3+0],
              meshpos[(size_t)a*3+1]-pos[(size_t)b*3+1],
              meshpos[(size_t)a*3+2]-pos[(size_t)b*3+2], sh2, EL2, e2);
  }
}

__global__ void gatherconvA_k(const float* __restrict__ emb, const int* __restrict__ an,
                              unsigned short* __restrict__ hi, unsigned short* __restrict__ lo){
  int idx = blockIdx.x*256 + threadIdx.x;
  if (idx >= N_*32) return;
  int n = idx >> 5, k = idx & 31;
  unsigned short h = 0, l = 0;
  if (k < 16) bf16split(emb[(size_t)an[n]*16 + k], h, l);
  hi[idx] = h; lo[idx] = l;
}

// ---------------- radial tables (fp32 path) ----------------
__global__ void es_k(float* __restrict__ Es){
  int idx = blockIdx.x*256 + threadIdx.x;
  if (idx >= NT_*64) return;
  int r = idx >> 6, k = idx & 63;
  const float step = 5.0f/63.0f;
  float d = (r*TH_ - k*step)/step;
  Es[idx] = expf(-d*d)*(8.0f/1.12f);
}

DEVI float lerp_tab(const float* __restrict__ T, float el, int O, int o){
  float u = el * (1.0f/TH_);
  u = fminf(u, (float)(NT_-1));
  int i = (int)u; if (i > NT_-2) i = NT_-2;
  float f = u - (float)i;
  float t0 = T[(size_t)i*O + o];
  float t1 = T[(size_t)(i+1)*O + o];
  return t0 + f*(t1 - t0);
}

struct BG {
  const float* A[5]; const float* B[5]; float* C[5];
  int K; int Nc[5];
};
template<int ACT>
__global__ __launch_bounds__(256) void bgemm_k(BG args){
  int chain = blockIdx.z;
  const float* A = args.A[chain];
  const float* Bm = args.B[chain];
  float* C = args.C[chain];
  int K = args.K, Nc = args.Nc[chain];
  int row0 = blockIdx.y*64, col0 = blockIdx.x*64;
  if (col0 >= Nc) return;
  __shared__ float As[16][72];
  __shared__ float Bs[16][72];
  int tid = threadIdx.x;
  int tx = tid & 15, ty = tid >> 4;
  float acc[4][4] = {};
  for (int k0 = 0; k0 < K; k0 += 16) {
    { int kk = tid & 15; int mloc = tid >> 4;
      int gk = k0 + kk;
      #pragma unroll
      for (int p = 0; p < 4; ++p) {
        int m = mloc + p*16; int gm = row0 + m;
        As[kk][m] = A[(size_t)gm*K + gk];
      } }
    { int nn = tid & 63; int kl = tid >> 6;
      #pragma unroll
      for (int p = 0; p < 4; ++p) {
        int kk = kl + p*4; int gk = k0 + kk; int gn = col0 + nn;
        Bs[kk][nn] = (gn < Nc) ? Bm[(size_t)gk*Nc + gn] : 0.0f;
      } }
    __syncthreads();
    #pragma unroll
    for (int kk = 0; kk < 16; ++kk) {
      float4 a4 = *(const float4*)&As[kk][ty*4];
      float4 b4 = *(const float4*)&Bs[kk][tx*4];
      float a[4] = {a4.x,a4.y,a4.z,a4.w};
      float b[4] = {b4.x,b4.y,b4.z,b4.w};
      #pragma unroll
      for (int i=0;i<4;++i)
        #pragma unroll
        for (int j=0;j<4;++j) acc[i][j] += a[i]*b[j];
    }
    __syncthreads();
  }
  for (int i=0;i<4;++i) {
    int gm = row0 + ty*4+i;
    for (int j=0;j<4;++j) {
      int gn = col0 + tx*4+j; if (gn >= Nc) continue;
      float v = acc[i][j];
      if (ACT==1) v = v*sigm(v);
      C[(size_t)gm*Nc + gn] = v;
    }
  }
}

// ---------------- MFMA bf16x3 path ----------------
__global__ void convA_k(const float* __restrict__ x, unsigned short* __restrict__ hi,
                        unsigned short* __restrict__ lo, int Mr, int K, int KP){
  int idx = blockIdx.x*256 + threadIdx.x;
  if (idx >= Mr*KP) return;
  int n = idx / KP, k = idx - n*KP;
  unsigned short h = 0, l = 0;
  if (k < K) bf16split(x[(size_t)n*K + k], h, l);
  hi[idx] = h; lo[idx] = l;
}

__global__ void convT_k(const float* __restrict__ B, unsigned short* __restrict__ hi,
                        unsigned short* __restrict__ lo, int K, int Nc, int KP){
  int idx = blockIdx.x*256 + threadIdx.x;
  if (idx >= Nc*KP) return;
  int n = idx / KP, k = idx - n*KP;
  unsigned short h = 0, l = 0;
  if (k < K) bf16split(B[(size_t)k*Nc + n], h, l);
  hi[idx] = h; lo[idx] = l;
}

// LDS-transposed expanded-weight reshape: dst[(s*O+o)*KP + f] = W[(f*9+s)*O+o]
// grid (KP/16, 9); coalesced reads (o-contiguous) and 32B-chunk writes (f-contiguous)
template<int O>
__global__ __launch_bounds__(256) void wreshapeT2_k(const float* __restrict__ W,
                           unsigned short* __restrict__ hi, unsigned short* __restrict__ lo,
                           int F, int KP){
  __shared__ float tile[16][O+1];
  int s = blockIdx.y;
  int f0 = blockIdx.x*16;
  for (int t = threadIdx.x; t < 16*O; t += 256){
    int f = t / O, o = t - f*O;
    int gf = f0 + f;
    tile[f][o] = (gf < F) ? W[(size_t)(gf*9+s)*O + o] : 0.0f;
  }
  __syncthreads();
  for (int t = threadIdx.x; t < 16*O; t += 256){
    int o = t >> 4, f = t & 15;
    unsigned short h, l;
    bf16split(tile[f][o], h, l);
    size_t di = (size_t)(s*O + o)*KP + f0 + f;
    hi[di] = h; lo[di] = l;
  }
}

__global__ void normact_bf_k(const float* __restrict__ x, unsigned short* __restrict__ hi,
                             unsigned short* __restrict__ lo){
  int idx = blockIdx.x*256 + threadIdx.x;
  if (idx >= N_*16) return;
  int n = idx >> 4, r = idx & 15;
  const float* xr = x + (size_t)n*144;
  unsigned short* hr = hi + (size_t)n*160;
  unsigned short* lr = lo + (size_t)n*160;
  unsigned short h, l;
  float s = xr[r];
  bf16split(s * sigm(fabsf(s)), h, l); hr[r]=h; lr[r]=l;
  float v0 = xr[16+r*3], v1 = xr[16+r*3+1], v2 = xr[16+r*3+2];
  float gv = sigm(sqrtf(v0*v0+v1*v1+v2*v2));
  bf16split(v0*gv,h,l); hr[16+r*3]=h;   lr[16+r*3]=l;
  bf16split(v1*gv,h,l); hr[16+r*3+1]=h; lr[16+r*3+1]=l;
  bf16split(v2*gv,h,l); hr[16+r*3+2]=h; lr[16+r*3+2]=l;
  float t0=xr[64+r*5],t1=xr[64+r*5+1],t2=xr[64+r*5+2],t3=xr[64+r*5+3],t4=xr[64+r*5+4];
  float gt = sigm(sqrtf(t0*t0+t1*t1+t2*t2+t3*t3+t4*t4));
  bf16split(t0*gt,h,l); hr[64+r*5]=h;   lr[64+r*5]=l;
  bf16split(t1*gt,h,l); hr[64+r*5+1]=h; lr[64+r*5+1]=l;
  bf16split(t2*gt,h,l); hr[64+r*5+2]=h; lr[64+r*5+2]=l;
  bf16split(t3*gt,h,l); hr[64+r*5+3]=h; lr[64+r*5+3]=l;
  bf16split(t4*gt,h,l); hr[64+r*5+4]=h; lr[64+r*5+4]=l;
  hr[144+r] = 0; lr[144+r] = 0;
}

DEVI f32x4 mfma3(const unsigned short* ah, const unsigned short* al,
                 const unsigned short* bh, const unsigned short* bl,
                 int KP, f32x4 acc){
  for (int k0 = 0; k0 < KP; k0 += 32) {
    bf16x8 a_h = *(const bf16x8*)(ah + k0);
    bf16x8 a_l = *(const bf16x8*)(al + k0);
    bf16x8 b_h = *(const bf16x8*)(bh + k0);
    bf16x8 b_l = *(const bf16x8*)(bl + k0);
    acc = __builtin_amdgcn_mfma_f32_16x16x32_bf16(a_h, b_h, acc, 0, 0, 0);
    acc = __builtin_amdgcn_mfma_f32_16x16x32_bf16(a_h, b_l, acc, 0, 0, 0);
    acc = __builtin_amdgcn_mfma_f32_16x16x32_bf16(a_l, b_h, acc, 0, 0, 0);
  }
  return acc;
}

__global__ __launch_bounds__(256) void mgemm_k(const unsigned short* __restrict__ Ah,
                     const unsigned short* __restrict__ Al,
                     const unsigned short* __restrict__ BTh,
                     const unsigned short* __restrict__ Bl,
                     float* __restrict__ C, int Mr, int KP, int Nc){
  int tilesN = Nc >> 4;
  int wid = ((blockIdx.x*256 + threadIdx.x) >> 6);
  int tm = wid / tilesN, tn = wid - tm*tilesN;
  if (tm*16 >= Mr) return;
  int lane = threadIdx.x & 63;
  int l15 = lane & 15;
  int kb  = (lane >> 4) * 8;
  f32x4 acc = {0.f,0.f,0.f,0.f};
  acc = mfma3(Ah + (size_t)(tm*16 + l15)*KP + kb, Al + (size_t)(tm*16 + l15)*KP + kb,
              BTh + (size_t)(tn*16 + l15)*KP + kb, Bl + (size_t)(tn*16 + l15)*KP + kb,
              KP, acc);
  int r0 = tm*16 + (lane>>4)*4;
  int co = tn*16 + l15;
  #pragma unroll
  for (int r = 0; r < 4; ++r) C[(size_t)(r0+r)*Nc + co] = acc[r];
}

__global__ __launch_bounds__(256) void mgemm2_k(const unsigned short* __restrict__ Ah,
                     const unsigned short* __restrict__ Al,
                     const unsigned short* __restrict__ B1h, const unsigned short* __restrict__ B1l,
                     float* __restrict__ C1, int N1,
                     const unsigned short* __restrict__ B2h, const unsigned short* __restrict__ B2l,
                     float* __restrict__ C2, int N2,
                     int KP){
  int tiles1 = N1 >> 4, tiles2 = N2 >> 4;
  int tilesN = tiles1 + tiles2;
  int wid = ((blockIdx.x*256 + threadIdx.x) >> 6);
  int tm = wid / tilesN, tn = wid - tm*tilesN;
  if (tm >= N_/16) return;
  const unsigned short* bh; const unsigned short* bl;
  float* C; int Nc; int tc;
  if (tn < tiles1){ bh = B1h; bl = B1l; C = C1; Nc = N1; tc = tn; }
  else            { bh = B2h; bl = B2l; C = C2; Nc = N2; tc = tn - tiles1; }
  int lane = threadIdx.x & 63;
  int l15 = lane & 15;
  int kb  = (lane >> 4) * 8;
  f32x4 acc = {0.f,0.f,0.f,0.f};
  acc = mfma3(Ah + (size_t)(tm*16 + l15)*KP + kb, Al + (size_t)(tm*16 + l15)*KP + kb,
              bh + (size_t)(tc*16 + l15)*KP + kb, bl + (size_t)(tc*16 + l15)*KP + kb,
              KP, acc);
  int r0 = tm*16 + (lane>>4)*4;
  int co = tc*16 + l15;
  #pragma unroll
  for (int r = 0; r < 4; ++r) C[(size_t)(r0+r)*Nc + co] = acc[r];
}

template<int O>
__global__ void econtract_k(const float* __restrict__ Y, const int* __restrict__ src,
                            const int* __restrict__ dst, const float* __restrict__ SH,
                            const float* __restrict__ EL, const float* __restrict__ T,
                            float* __restrict__ out, int nE){
  int idx = blockIdx.x*256 + threadIdx.x;
  if (idx >= nE*O) return;
  int e = idx / O, o = idx - e*O;
  const float* sr = SH + (size_t)e*9;
  const float* yr = Y + (size_t)src[e]*(9*O) + o;
  float acc = 0.0f;
  #pragma unroll
  for (int s = 0; s < 9; ++s) acc += sr[s] * yr[s*O];
  float rv = lerp_tab(T, EL[e], O, o);
  atomicAdd(&out[(size_t)dst[e]*O + o], acc * rv);
}

// ---------------- FNO ----------------
__global__ void fc0_k(const float* __restrict__ mf, const float* __restrict__ Wt,
                      const float* __restrict__ bb, float* __restrict__ h){
  int idx = blockIdx.x*256 + threadIdx.x;
  if (idx >= M_*16) return;
  int m = idx >> 4, o = idx & 15;
  int r = m % 8000;
  float fx = (float)(r/400)*0.05f, fy = (float)((r/20)%20)*0.05f, fz = (float)(r%20)*0.05f;
  const float* mfr = mf + (size_t)m*32;
  float acc = bb[o];
  #pragma unroll
  for (int j=0;j<32;++j){
    float v = mfr[j];
    v = v * sigm(fabsf(v));
    acc += v*Wt[j*16+o];
  }
  acc += fx*Wt[32*16+o] + fy*Wt[33*16+o] + fz*Wt[34*16+o];
  h[idx] = acc;
}

__global__ __launch_bounds__(256) void wreorder2_k(const float* __restrict__ wr, const float* __restrict__ wi,
                          float2* __restrict__ W2){
  __shared__ float2 tile[2560];
  int l = blockIdx.y;
  const float* wrl = wr + (size_t)l*1024000;
  const float* wil = wi + (size_t)l*1024000;
  int p = blockIdx.x;
  int ky = p/20, kx = p%20;
  int corner = ((kx>=10)?1:0) + ((ky>=10)?2:0);
  int base2 = corner*256;
  int soff = (kx%10)*100 + (ky%10)*10;
  for (int t = threadIdx.x; t < 2560; t += 256){
    int chunk = t/10, kz = t - chunk*10;
    size_t src = (size_t)(base2 + chunk)*1000 + soff + kz;
    tile[kz*256 + chunk] = make_float2(wrl[src], wil[src]);
  }
  __syncthreads();
  float2* dst = W2 + (size_t)l*1024000 + (size_t)p*2560;
  for (int t = threadIdx.x; t < 2560; t += 256) dst[t] = tile[t];
}

// stage A: z-DFT + y-DFT, 2 channels per block (grid 1280)
__global__ __launch_bounds__(256) void zyfwd2_k(const float* __restrict__ h, float2* __restrict__ cA){
  __shared__ float  pl[20][20][2];
  __shared__ float2 tz[20][10][2];
  __shared__ float2 tw[20];
  int tid = threadIdx.x;
  if (tid < 20){ float a = -6.283185307179586f*tid/20.0f; tw[tid] = make_float2(cosf(a), sinf(a)); }
  int bid = blockIdx.x;
  int b = bid / 160, rem = bid % 160;
  int X = rem >> 3, cg = rem & 7;
  const float* hp = h + (size_t)(b*20+X)*400*16 + cg*2;
  for (int t = tid; t < 400; t += 256) {
    int y = t/20, z = t%20;
    const float2 v = *(const float2*)(hp + (size_t)t*16);
    pl[y][z][0]=v.x; pl[y][z][1]=v.y;
  }
  __syncthreads();
  for (int t = tid; t < 400; t += 256) {
    int y = t/20, r2 = t%20;
    int kz = r2 >> 1, c = r2 & 1;
    float sr=0.0f, si=0.0f; int j=0;
    for (int z=0; z<20; ++z){
      float v = pl[y][z][c];
      float2 w = tw[j];
      sr += v*w.x; si += v*w.y;
      j += kz; if (j>=20) j-=20;
    }
    tz[y][kz][c] = make_float2(sr,si);
  }
  __syncthreads();
  for (int t = tid; t < 400; t += 256) {
    int ky = t/20, r2 = t%20;
    int kz = r2 >> 1, c = r2 & 1;
    float sr=0.0f, si=0.0f; int j=0;
    for (int y=0; y<20; ++y){
      float2 v = tz[y][kz][c];
      float2 w = tw[j];
      sr += v.x*w.x - v.y*w.y;
      si += v.x*w.y + v.y*w.x;
      j += ky; if (j>=20) j-=20;
    }
    cA[((size_t)((b*20+ky)*10+kz)*20 + X)*16 + cg*2+c] = make_float2(sr,si);
  }
}

__global__ __launch_bounds__(256) void xmix_k(const float2* __restrict__ cA, float2* __restrict__ cB,
                    const float2* __restrict__ W2){
  __shared__ float2 xin[16][20];
  __shared__ float2 Xf[20][16];
  __shared__ float2 Mx[20][16];
  __shared__ float2 twf[20], twi[20];
  int tid = threadIdx.x;
  if (tid < 20){
    float a = -6.283185307179586f*tid/20.0f;
    twf[tid] = make_float2(cosf(a), sinf(a));
    twi[tid] = make_float2(cosf(a), -sinf(a));
  }
  int bid = blockIdx.x;
  int b = bid/200, rem = bid%200;
  int ky = rem/10, kz = rem%10;
  const float2* src = cA + (size_t)((b*20+ky)*10+kz)*320;
  for (int t = tid; t < 320; t += 256){
    int x = t/16, i = t%16;
    xin[i][x] = src[t];
  }
  __syncthreads();
  for (int t = tid; t < 320; t += 256){
    int kx = t/16, i = t%16;
    float sr=0.0f, si=0.0f; int j=0;
    for (int x=0;x<20;++x){
      float2 v = xin[i][x]; float2 w = twf[j];
      sr += v.x*w.x - v.y*w.y; si += v.x*w.y + v.y*w.x;
      j += kx; if (j>=20) j-=20;
    }
    Xf[kx][i] = make_float2(sr,si);
  }
  __syncthreads();
  for (int t = tid; t < 320; t += 256){
    int kx = t/16, o = t%16;
    const float2* wp = W2 + ((size_t)(ky*20+kx)*10 + kz)*256 + o;
    float sr=0.0f, si=0.0f;
    #pragma unroll
    for (int i=0;i<16;++i){
      float2 a = Xf[kx][i];
      float2 w = wp[i*16];
      sr += a.x*w.x - a.y*w.y;
      si += a.x*w.y + a.y*w.x;
    }
    Mx[kx][o] = make_float2(sr,si);
  }
  __syncthreads();
  for (int t = tid; t < 320; t += 256){
    int x = t/16, o = t%16;
    float sr=0.0f, si=0.0f; int j=0;
    for (int kx=0;kx<20;++kx){
      float2 v = Mx[kx][o]; float2 w = twi[j];
      sr += v.x*w.x - v.y*w.y; si += v.x*w.y + v.y*w.x;
      j += x; if (j>=20) j-=20;
    }
    cB[((size_t)((b*20+x)*20+ky)*10+kz)*16 + o] = make_float2(sr,si);
  }
}

// stage C: y-inv + z-inv(real), 2 channels per block (grid 1280)
__global__ __launch_bounds__(256) void yzinv2_k(const float2* __restrict__ cB, float* __restrict__ spec){
  __shared__ float2 ci[20][10][2];
  __shared__ float2 ty[20][10][2];
  __shared__ float2 twi[20];
  int tid = threadIdx.x;
  if (tid < 20){ float a = 6.283185307179586f*tid/20.0f; twi[tid] = make_float2(cosf(a), sinf(a)); }
  int bid = blockIdx.x;
  int b = bid/160, rem = bid%160;
  int X = rem>>3, cg = rem&7;
  const float2* src = cB + (size_t)(b*20+X)*200*16;
  for (int t = tid; t < 400; t += 256){
    int ky = t/20, r2 = t%20;
    int kz = r2 >> 1, c = r2 & 1;
    ci[ky][kz][c] = src[(size_t)(ky*10+kz)*16 + cg*2+c];
  }
  __syncthreads();
  for (int t = tid; t < 400; t += 256){
    int y = t/20, r2 = t%20;
    int kz = r2 >> 1, c = r2 & 1;
    float sr=0.0f, si=0.0f; int j=0;
    for (int ky=0;ky<20;++ky){
      float2 v = ci[ky][kz][c]; float2 w = twi[j];
      sr += v.x*w.x - v.y*w.y; si += v.x*w.y + v.y*w.x;
      j += y; if (j>=20) j-=20;
    }
    ty[y][kz][c] = make_float2(sr,si);
  }
  __syncthreads();
  float* dst = spec + (size_t)(b*20+X)*400*16 + cg*2;
  for (int t = tid; t < 800; t += 256){
    int y = t/40, r2 = t%40;
    int z = r2 >> 1, c = r2 & 1;
    float acc = ty[y][0][c].x;
    float a2 = 0.0f; int jj = 0;
    for (int kz=1; kz<10; ++kz){
      jj += z; if (jj>=20) jj-=20;
      float2 v = ty[y][kz][c]; float2 w = twi[jj];
      a2 += v.x*w.x - v.y*w.y;
    }
    acc += 2.0f*a2;
    dst[(size_t)(y*20+z)*16 + c] = acc * (1.0f/8000.0f);
  }
}

// fused FNO tail, 64 rows/block, 128 threads (grid 1000)
__global__ __launch_bounds__(128) void ffn4_k(const float* __restrict__ spec, const float* __restrict__ h,
                     const float* __restrict__ pw, const float* __restrict__ ff1,
                     const float* __restrict__ ff2, float* __restrict__ hout){
  __shared__ float spw[256];
  __shared__ float sf1[1024];
  __shared__ float sf2[1024];
  __shared__ float h2s[64][17];
  __shared__ float red[2][64][17];
  int tid = threadIdx.x;
  for (int t = tid; t < 256; t += 128) spw[t] = pw[t];
  for (int t = tid; t < 1024; t += 128){ sf1[t]=ff1[t]; sf2[t]=ff2[t]; }
  int rl = tid >> 1, q = tid & 1;
  int m = blockIdx.x*64 + rl;
  const float* hr = h + (size_t)m*16;
  float hl[16];
  #pragma unroll
  for (int i=0;i<16;++i) hl[i] = hr[i];
  __syncthreads();
  const float* sp = spec + (size_t)m*16;
  #pragma unroll
  for (int c=0;c<8;++c){
    int o = q*8+c;
    float acc = sp[o];
    #pragma unroll
    for (int i=0;i<16;++i) acc += hl[i]*spw[i*16+o];
    h2s[rl][o] = geluf(acc);
  }
  __syncthreads();
  float h2l[16];
  #pragma unroll
  for (int i=0;i<16;++i) h2l[i] = h2s[rl][i];
  float part[16] = {};
  for (int kk=0;kk<32;++kk){
    int k = q*32+kk;
    float a0=0.0f, a1=0.0f;
    #pragma unroll
    for (int i=0;i<8;++i){ a0 += h2l[i]*sf1[i*64+k]; a1 += h2l[8+i]*sf1[(8+i)*64+k]; }
    float tk = geluf(a0+a1);
    #pragma unroll
    for (int o=0;o<16;++o) part[o] += tk*sf2[k*16+o];
  }
  #pragma unroll
  for (int o=0;o<16;++o) red[q][rl][o] = part[o];
  __syncthreads();
  #pragma unroll
  for (int c=0;c<8;++c){
    int o = q*8+c;
    hout[(size_t)m*16+o] = h2s[rl][o] + red[0][rl][o] + red[1][rl][o];
  }
}

// fused final projection, 64 rows/block, 128 threads (grid 1000)
__global__ __launch_bounds__(128) void fctail4_k(const float* __restrict__ h, const float* __restrict__ fc1,
                        const float* __restrict__ fc2, float* __restrict__ outm){
  __shared__ float s1[2048];
  __shared__ float s2[2048];
  __shared__ float red[2][64][17];
  int tid = threadIdx.x;
  for (int t = tid; t < 2048; t += 128){ s1[t]=fc1[t]; s2[t]=fc2[t]; }
  int rl = tid >> 1, q = tid & 1;
  int m = blockIdx.x*64 + rl;
  const float* hr = h + (size_t)m*16;
  float hl[16];
  #pragma unroll
  for (int i=0;i<16;++i) hl[i] = hr[i];
  __syncthreads();
  float part[16] = {};
  for (int kk=0;kk<64;++kk){
    int k = q*64+kk;
    float a0=0.0f, a1=0.0f;
    #pragma unroll
    for (int i=0;i<8;++i){ a0 += hl[i]*s1[i*128+k]; a1 += hl[8+i]*s1[(8+i)*128+k]; }
    float tk = geluf(a0+a1);
    #pragma unroll
    for (int o=0;o<16;++o) part[o] += tk*s2[k*16+o];
  }
  #pragma unroll
  for (int o=0;o<16;++o) red[q][rl][o] = part[o];
  __syncthreads();
  #pragma unroll
  for (int c=0;c<8;++c){
    int o = q*8+c;
    outm[(size_t)m*16+o] = red[0][rl][o] + red[1][rl][o];
  }
}

// ---------------- m2a + final ----------------
__global__ void m2a_k(const float* __restrict__ mf2, const int* __restrict__ mdst,
                      const int* __restrict__ asrc, const float* __restrict__ sh2,
                      const float* __restrict__ Wt, const float* __restrict__ EL,
                      const float* __restrict__ T, float* __restrict__ af){
  int e = blockIdx.x*256 + threadIdx.x;
  if (e >= E2_) return;
  const float* xr = mf2 + (size_t)mdst[e]*16;
  const float* sr = sh2 + (size_t)e*9;
  float sh[9];
  #pragma unroll
  for (int s=0;s<9;++s) sh[s] = sr[s];
  float acc = 0.0f;
  #pragma unroll
  for (int f=0;f<16;++f) {
    float xv = xr[f];
    float dot = 0.0f;
    #pragma unroll
    for (int s=0;s<9;++s) dot += sh[s]*Wt[f*9+s];
    acc += xv*dot;
  }
  float rv = lerp_tab(T, EL[e], 1, 0);
  atomicAdd(&af[asrc[e]], acc*rv);
}

__global__ void bsum_k(const float* __restrict__ af, const int* __restrict__ batch,
                       float* __restrict__ out){
  int n = blockIdx.x*256 + threadIdx.x;
  if (n >= N_) return;
  atomicAdd(&out[batch[n]], af[n]);
}

} // namespace

extern "C" void kernel_launch(void* const* d_in, const int* in_sizes, int n_in,
                              void* d_out, int out_size, void* d_ws, size_t ws_size,
                              hipStream_t stream) {
  (void)in_sizes; (void)n_in; (void)out_size; (void)ws_size;
  const float* pos   = (const float*)d_in[0];
  const float* cell  = (const float*)d_in[1];
  const int*   an    = (const int*)d_in[2];
  const int*   batch = (const int*)d_in[3];
  const int*   esrc  = (const int*)d_in[4];
  const int*   edst  = (const int*)d_in[5];
  const int*   asrc  = (const int*)d_in[6];
  const int*   mdst  = (const int*)d_in[7];
  const float* emb   = (const float*)d_in[8];
  const float* g0_W  = (const float*)d_in[9];
  const float* g0_Wsc= (const float*)d_in[10];
  const float* g0_m1 = (const float*)d_in[11];
  const float* g0_m2 = (const float*)d_in[12];
  const float* g0_m3 = (const float*)d_in[13];
  const float* g12_W = (const float*)d_in[14];
  const float* g12_Wsc=(const float*)d_in[15];
  const float* g12_m1= (const float*)d_in[16];
  const float* g12_m2= (const float*)d_in[17];
  const float* g12_m3= (const float*)d_in[18];
  const float* a2m_W = (const float*)d_in[19];
  const float* a2m_m1= (const float*)d_in[20];
  const float* a2m_m2= (const float*)d_in[21];
  const float* a2m_m3= (const float*)d_in[22];
  const float* m2a_W = (const float*)d_in[23];
  const float* m2a_m1= (const float*)d_in[24];
  const float* m2a_m2= (const float*)d_in[25];
  const float* m2a_m3= (const float*)d_in[26];
  const float* fc0_W = (const float*)d_in[27];
  const float* fc0_b = (const float*)d_in[28];
  const float* sw_r  = (const float*)d_in[29];
  const float* sw_i  = (const float*)d_in[30];
  const float* pw    = (const float*)d_in[31];
  const float* ff1   = (const float*)d_in[32];
  const float* ff2   = (const float*)d_in[33];
  const float* fc1   = (const float*)d_in[34];
  const float* fc2   = (const float*)d_in[35];
  float* out = (float*)d_out;

  float* Wp = (float*)d_ws;
  size_t off = 0;
  auto alloc = [&](size_t n){ off = (off+3)&~(size_t)3; float* p = Wp + off; off += n; return p; };
  float* meshpos = alloc((size_t)M_*3);
  float* she   = alloc((size_t)E_*9);
  float* ELe   = alloc((size_t)E_);
  float* sh2   = alloc((size_t)E2_*9);
  float* EL2   = alloc((size_t)E2_);
  float* xatom = alloc((size_t)N_*144);
  float* Yg    = alloc((size_t)N_*1296);
  float* mf    = alloc((size_t)M_*32);
  float* hbuf  = alloc((size_t)M_*16);
  float* htmp  = alloc((size_t)M_*16);
  float2* cA   = (float2*)alloc(1024000);
  float2* cB   = (float2*)alloc(1024000);
  float2* W2   = (float2*)alloc((size_t)3*2048000);
  float* af    = alloc((size_t)N_);
  float* Es    = alloc((size_t)NT_*64);
  float* H1g   = alloc((size_t)5*NT_*128);
  float* H2g   = alloc((size_t)5*NT_*128);
  float* T0    = alloc((size_t)NT_*144);
  float* T1    = alloc((size_t)NT_*144);
  float* T2    = alloc((size_t)NT_*144);
  float* T3    = alloc((size_t)NT_*32);
  float* T4    = alloc((size_t)NT_*1);
  unsigned short* Ah  = (unsigned short*)alloc((size_t)N_*160/2);
  unsigned short* Al  = (unsigned short*)alloc((size_t)N_*160/2);
  unsigned short* BTh = (unsigned short*)alloc((size_t)1296*160/2);
  unsigned short* BTl = (unsigned short*)alloc((size_t)1296*160/2);
  unsigned short* BWh = (unsigned short*)alloc((size_t)144*160/2);
  unsigned short* BWl = (unsigned short*)alloc((size_t)144*160/2);

  auto g1 = [](int n){ return dim3((unsigned)((n+255)/256)); };
  auto mg = [](int tiles){ return dim3((unsigned)((tiles+3)/4)); };
  const int TM = N_/16;

  // zero accumulators (single launch)
  zero3_k<<<g1(M_*32), 256, 0, stream>>>(out, af, mf);

  // geometry
  meshpos_k<<<g1(M_), 256, 0, stream>>>(cell, meshpos);
  edge_both_k<<<g1(E_+E2_), 256, 0, stream>>>(pos, meshpos, esrc, edst, asrc, mdst,
                                              she, ELe, sh2, EL2);
  gatherconvA_k<<<g1(N_*32), 256, 0, stream>>>(emb, an, Ah, Al);

  // spectral weight reorder
  wreorder2_k<<<dim3(400,3), 256, 0, stream>>>(sw_r, sw_i, W2);

  // ---- radial tables via 3 batched fp32 GEMMs ----
  {
    es_k<<<g1(NT_*64), 256, 0, stream>>>(Es);
    BG l1, l2, l3;
    const float* m1s[5] = {g0_m1, g12_m1, g12_m1+(size_t)64*128, a2m_m1, m2a_m1};
    const float* m2s[5] = {g0_m2, g12_m2, g12_m2+(size_t)128*128, a2m_m2, m2a_m2};
    const float* m3s[5] = {g0_m3, g12_m3, g12_m3+(size_t)128*144, a2m_m3, m2a_m3};
    float* Ts[5] = {T0, T1, T2, T3, T4};
    int NOs[5] = {144, 144, 144, 32, 1};
    for (int c = 0; c < 5; ++c) {
      l1.A[c] = Es;                      l1.B[c] = m1s[c]; l1.C[c] = H1g + (size_t)c*NT_*128; l1.Nc[c] = 128;
      l2.A[c] = H1g + (size_t)c*NT_*128; l2.B[c] = m2s[c]; l2.C[c] = H2g + (size_t)c*NT_*128; l2.Nc[c] = 128;
      l3.A[c] = H2g + (size_t)c*NT_*128; l3.B[c] = m3s[c]; l3.C[c] = Ts[c];                   l3.Nc[c] = NOs[c];
    }
    l1.K = 64; l2.K = 128; l3.K = 128;
    bgemm_k<1><<<dim3(2, NT_/64, 5), 256, 0, stream>>>(l1);
    bgemm_k<1><<<dim3(2, NT_/64, 5), 256, 0, stream>>>(l2);
    bgemm_k<0><<<dim3(3, NT_/64, 5), 256, 0, stream>>>(l3);
  }

  // ---- g0 (KP=32) ----
  wreshapeT2_k<144><<<dim3(2,9), 256, 0, stream>>>(g0_W, BTh, BTl, 16, 32);
  convT_k<<<g1(144*32), 256, 0, stream>>>(g0_Wsc, BWh, BWl, 16, 144, 32);
  mgemm2_k<<<mg(TM*90), 256, 0, stream>>>(Ah, Al, BTh, BTl, Yg, 1296,
                                          BWh, BWl, xatom, 144, 32);
  econtract_k<144><<<g1(E_*144), 256, 0, stream>>>(Yg, esrc, edst, she, ELe, T0, xatom, E_);

  // ---- g12 x2 (KP=160) ----
  for (int i = 0; i < 2; ++i) {
    normact_bf_k<<<g1(N_*16), 256, 0, stream>>>(xatom, Ah, Al);
    wreshapeT2_k<144><<<dim3(10,9), 256, 0, stream>>>(g12_W + (size_t)i*1296*144, BTh, BTl, 144, 160);
    convT_k<<<g1(144*160), 256, 0, stream>>>(g12_Wsc + (size_t)i*144*144, BWh, BWl, 144, 144, 160);
    mgemm2_k<<<mg(TM*90), 256, 0, stream>>>(Ah, Al, BTh, BTl, Yg, 1296,
                                            BWh, BWl, xatom, 144, 160);
    econtract_k<144><<<g1(E_*144), 256, 0, stream>>>(Yg, esrc, edst, she, ELe, (i==0)?T1:T2, xatom, E_);
  }

  // ---- a2m (KP=160) ----
  convA_k<<<g1(N_*160), 256, 0, stream>>>(xatom, Ah, Al, N_, 144, 160);
  wreshapeT2_k<32><<<dim3(10,9), 256, 0, stream>>>(a2m_W, BTh, BTl, 144, 160);
  mgemm_k<<<mg(TM*18), 256, 0, stream>>>(Ah, Al, BTh, BTl, Yg, N_, 160, 288);
  econtract_k<32><<<g1(E2_*32), 256, 0, stream>>>(Yg, asrc, mdst, sh2, EL2, T3, mf, E2_);

  // ---- FNO ----
  fc0_k<<<g1(M_*16), 256, 0, stream>>>(mf, fc0_W, fc0_b, hbuf);
  for (int l = 0; l < 3; ++l) {
    zyfwd2_k<<<dim3(1280), 256, 0, stream>>>(hbuf, cA);
    xmix_k<<<dim3(1600), 256, 0, stream>>>(cA, cB, W2 + (size_t)l*1024000);
    yzinv2_k<<<dim3(1280), 256, 0, stream>>>(cB, htmp);
    ffn4_k<<<dim3(1000), 128, 0, stream>>>(htmp, hbuf, pw + (size_t)l*256,
                                           ff1 + (size_t)l*1024, ff2 + (size_t)l*1024, hbuf);
  }
  fctail4_k<<<dim3(1000), 128, 0, stream>>>(hbuf, fc1, fc2, htmp);

  // ---- m2a + batch reduce ----
  m2a_k<<<g1(E2_), 256, 0, stream>>>(htmp, mdst, asrc, sh2, m2a_W, EL2, T4, af);
  bsum_k<<<g1(N_), 256, 0, stream>>>(af, batch, out);
}

// Round 16
// 493.048 us; speedup vs baseline: 1.0360x; 1.0360x over previous
//
#include <hip/hip_runtime.h>
#include <math.h>

#define DEVI __device__ __forceinline__

namespace {

constexpr int N_  = 2048;
constexpr int E_  = 32768;
constexpr int E2_ = 65536;
constexpr int M_  = 64000;   // 8 * 20^3
constexpr int NT_ = 2048;    // radial table resolution
constexpr float TMAX_ = 5.5f;
constexpr float TH_ = TMAX_ / NT_;

using bf16x8 = __attribute__((ext_vector_type(8))) short;
using f32x4  = __attribute__((ext_vector_type(4))) float;

DEVI float sigm(float x)  { return 1.0f/(1.0f+expf(-x)); }
DEVI float geluf(float x) {
  float t = tanhf(0.7978845608028654f*(x + 0.044715f*x*x*x));
  return 0.5f*x*(1.0f+t);
}

DEVI unsigned short bf16rn(float x){
  unsigned u = __float_as_uint(x);
  unsigned r = u + 0x7FFFu + ((u>>16)&1u);
  return (unsigned short)(r>>16);
}
DEVI void bf16split(float x, unsigned short& h, unsigned short& l){
  h = bf16rn(x);
  float hf = __uint_as_float(((unsigned)h)<<16);
  l = bf16rn(x - hf);
}

// ---------------- utility ----------------
__global__ void zero3_k(float* __restrict__ out, float* __restrict__ af,
                        float* __restrict__ mf){
  int i = blockIdx.x*256 + threadIdx.x;
  if (i < 8) out[i] = 0.0f;
  if (i < N_) af[i] = 0.0f;
  if (i < M_*32) mf[i] = 0.0f;
}

__global__ void meshpos_k(const float* __restrict__ cell, float* __restrict__ mp){
  int m = blockIdx.x*256 + threadIdx.x;
  if (m >= M_) return;
  int b = m/8000, r = m%8000;
  float fx = (float)(r/400)    * 0.05f;
  float fy = (float)((r/20)%20)* 0.05f;
  float fz = (float)(r%20)     * 0.05f;
  const float* c = cell + b*9;
  mp[(size_t)m*3+0] = fx*c[0] + fy*c[3] + fz*c[6];
  mp[(size_t)m*3+1] = fx*c[1] + fy*c[4] + fz*c[7];
  mp[(size_t)m*3+2] = fx*c[2] + fy*c[5] + fz*c[8];
}

DEVI void edge_core(float ex, float ey, float ez, float* s, float* el_out, int e){
  float el = sqrtf(ex*ex+ey*ey+ez*ez) + 1e-8f;
  el_out[e] = el;
  float x = ex/el, y = ey/el, z = ez/el;
  float* sp = s + (size_t)e*9;
  sp[0] = 0.28209479177387814f;
  sp[1] = 0.4886025119029199f*y;
  sp[2] = 0.4886025119029199f*z;
  sp[3] = 0.4886025119029199f*x;
  sp[4] = 1.0925484305920792f*x*y;
  sp[5] = 1.0925484305920792f*y*z;
  sp[6] = 0.31539156525252005f*(3.0f*z*z-1.0f);
  sp[7] = 1.0925484305920792f*x*z;
  sp[8] = 0.5462742152960396f*(x*x-y*y);
}

__global__ void edge_both_k(const float* __restrict__ pos, const float* __restrict__ meshpos,
                            const int* __restrict__ esrc, const int* __restrict__ edst,
                            const int* __restrict__ asrc, const int* __restrict__ mdst,
                            float* __restrict__ she, float* __restrict__ ELe,
                            float* __restrict__ sh2, float* __restrict__ EL2){
  int e = blockIdx.x*256 + threadIdx.x;
  if (e < E_){
    int a = esrc[e], b = edst[e];
    edge_core(pos[(size_t)a*3+0]-pos[(size_t)b*3+0],
              pos[(size_t)a*3+1]-pos[(size_t)b*3+1],
              pos[(size_t)a*3+2]-pos[(size_t)b*3+2], she, ELe, e);
  } else if (e < E_ + E2_){
    int e2 = e - E_;
    int a = mdst[e2], b = asrc[e2];
    edge_core(meshpos[(size_t)a*3+0]-pos[(size_t)b*3+0],
              meshpos[(size_t)a*3+1]-pos[(size_t)b*3+1],
              meshpos[(size_t)a*3+2]-pos[(size_t)b*3+2], sh2, EL2, e2);
  }
}

__global__ void gatherconvA_k(const float* __restrict__ emb, const int* __restrict__ an,
                              unsigned short* __restrict__ hi, unsigned short* __restrict__ lo){
  int idx = blockIdx.x*256 + threadIdx.x;
  if (idx >= N_*32) return;
  int n = idx >> 5, k = idx & 31;
  unsigned short h = 0, l = 0;
  if (k < 16) bf16split(emb[(size_t)an[n]*16 + k], h, l);
  hi[idx] = h; lo[idx] = l;
}

// ---------------- radial tables (fp32 path) ----------------
__global__ void es_k(float* __restrict__ Es){
  int idx = blockIdx.x*256 + threadIdx.x;
  if (idx >= NT_*64) return;
  int r = idx >> 6, k = idx & 63;
  const float step = 5.0f/63.0f;
  float d = (r*TH_ - k*step)/step;
  Es[idx] = expf(-d*d)*(8.0f/1.12f);
}

DEVI float lerp_tab(const float* __restrict__ T, float el, int O, int o){
  float u = el * (1.0f/TH_);
  u = fminf(u, (float)(NT_-1));
  int i = (int)u; if (i > NT_-2) i = NT_-2;
  float f = u - (float)i;
  float t0 = T[(size_t)i*O + o];
  float t1 = T[(size_t)(i+1)*O + o];
  return t0 + f*(t1 - t0);
}

struct BG {
  const float* A[5]; const float* B[5]; float* C[5];
  int K; int Nc[5];
};
template<int ACT>
__global__ __launch_bounds__(256) void bgemm_k(BG args){
  int chain = blockIdx.z;
  const float* A = args.A[chain];
  const float* Bm = args.B[chain];
  float* C = args.C[chain];
  int K = args.K, Nc = args.Nc[chain];
  int row0 = blockIdx.y*64, col0 = blockIdx.x*64;
  if (col0 >= Nc) return;
  __shared__ float As[16][72];
  __shared__ float Bs[16][72];
  int tid = threadIdx.x;
  int tx = tid & 15, ty = tid >> 4;
  float acc[4][4] = {};
  for (int k0 = 0; k0 < K; k0 += 16) {
    { int kk = tid & 15; int mloc = tid >> 4;
      int gk = k0 + kk;
      #pragma unroll
      for (int p = 0; p < 4; ++p) {
        int m = mloc + p*16; int gm = row0 + m;
        As[kk][m] = A[(size_t)gm*K + gk];
      } }
    { int nn = tid & 63; int kl = tid >> 6;
      #pragma unroll
      for (int p = 0; p < 4; ++p) {
        int kk = kl + p*4; int gk = k0 + kk; int gn = col0 + nn;
        Bs[kk][nn] = (gn < Nc) ? Bm[(size_t)gk*Nc + gn] : 0.0f;
      } }
    __syncthreads();
    #pragma unroll
    for (int kk = 0; kk < 16; ++kk) {
      float4 a4 = *(const float4*)&As[kk][ty*4];
      float4 b4 = *(const float4*)&Bs[kk][tx*4];
      float a[4] = {a4.x,a4.y,a4.z,a4.w};
      float b[4] = {b4.x,b4.y,b4.z,b4.w};
      #pragma unroll
      for (int i=0;i<4;++i)
        #pragma unroll
        for (int j=0;j<4;++j) acc[i][j] += a[i]*b[j];
    }
    __syncthreads();
  }
  for (int i=0;i<4;++i) {
    int gm = row0 + ty*4+i;
    for (int j=0;j<4;++j) {
      int gn = col0 + tx*4+j; if (gn >= Nc) continue;
      float v = acc[i][j];
      if (ACT==1) v = v*sigm(v);
      C[(size_t)gm*Nc + gn] = v;
    }
  }
}

// ---------------- MFMA bf16x3 path ----------------
__global__ void convA_k(const float* __restrict__ x, unsigned short* __restrict__ hi,
                        unsigned short* __restrict__ lo, int Mr, int K, int KP){
  int idx = blockIdx.x*256 + threadIdx.x;
  if (idx >= Mr*KP) return;
  int n = idx / KP, k = idx - n*KP;
  unsigned short h = 0, l = 0;
  if (k < K) bf16split(x[(size_t)n*K + k], h, l);
  hi[idx] = h; lo[idx] = l;
}

__global__ void convT_k(const float* __restrict__ B, unsigned short* __restrict__ hi,
                        unsigned short* __restrict__ lo, int K, int Nc, int KP){
  int idx = blockIdx.x*256 + threadIdx.x;
  if (idx >= Nc*KP) return;
  int n = idx / KP, k = idx - n*KP;
  unsigned short h = 0, l = 0;
  if (k < K) bf16split(B[(size_t)k*Nc + n], h, l);
  hi[idx] = h; lo[idx] = l;
}

template<int O>
__global__ void wreshapeT_k(const float* __restrict__ W, unsigned short* __restrict__ hi,
                            unsigned short* __restrict__ lo, int F, int KP){
  int idx = blockIdx.x*256 + threadIdx.x;
  int total = 9*O*KP;
  if (idx >= total) return;
  int n = idx / KP, f = idx - n*KP;
  unsigned short h = 0, l = 0;
  if (f < F){
    int s = n / O, o = n - s*O;
    bf16split(W[(size_t)(f*9+s)*O + o], h, l);
  }
  hi[idx] = h; lo[idx] = l;
}

__global__ void normact_bf_k(const float* __restrict__ x, unsigned short* __restrict__ hi,
                             unsigned short* __restrict__ lo){
  int idx = blockIdx.x*256 + threadIdx.x;
  if (idx >= N_*16) return;
  int n = idx >> 4, r = idx & 15;
  const float* xr = x + (size_t)n*144;
  unsigned short* hr = hi + (size_t)n*160;
  unsigned short* lr = lo + (size_t)n*160;
  unsigned short h, l;
  float s = xr[r];
  bf16split(s * sigm(fabsf(s)), h, l); hr[r]=h; lr[r]=l;
  float v0 = xr[16+r*3], v1 = xr[16+r*3+1], v2 = xr[16+r*3+2];
  float gv = sigm(sqrtf(v0*v0+v1*v1+v2*v2));
  bf16split(v0*gv,h,l); hr[16+r*3]=h;   lr[16+r*3]=l;
  bf16split(v1*gv,h,l); hr[16+r*3+1]=h; lr[16+r*3+1]=l;
  bf16split(v2*gv,h,l); hr[16+r*3+2]=h; lr[16+r*3+2]=l;
  float t0=xr[64+r*5],t1=xr[64+r*5+1],t2=xr[64+r*5+2],t3=xr[64+r*5+3],t4=xr[64+r*5+4];
  float gt = sigm(sqrtf(t0*t0+t1*t1+t2*t2+t3*t3+t4*t4));
  bf16split(t0*gt,h,l); hr[64+r*5]=h;   lr[64+r*5]=l;
  bf16split(t1*gt,h,l); hr[64+r*5+1]=h; lr[64+r*5+1]=l;
  bf16split(t2*gt,h,l); hr[64+r*5+2]=h; lr[64+r*5+2]=l;
  bf16split(t3*gt,h,l); hr[64+r*5+3]=h; lr[64+r*5+3]=l;
  bf16split(t4*gt,h,l); hr[64+r*5+4]=h; lr[64+r*5+4]=l;
  hr[144+r] = 0; lr[144+r] = 0;
}

DEVI f32x4 mfma3(const unsigned short* ah, const unsigned short* al,
                 const unsigned short* bh, const unsigned short* bl,
                 int KP, f32x4 acc){
  for (int k0 = 0; k0 < KP; k0 += 32) {
    bf16x8 a_h = *(const bf16x8*)(ah + k0);
    bf16x8 a_l = *(const bf16x8*)(al + k0);
    bf16x8 b_h = *(const bf16x8*)(bh + k0);
    bf16x8 b_l = *(const bf16x8*)(bl + k0);
    acc = __builtin_amdgcn_mfma_f32_16x16x32_bf16(a_h, b_h, acc, 0, 0, 0);
    acc = __builtin_amdgcn_mfma_f32_16x16x32_bf16(a_h, b_l, acc, 0, 0, 0);
    acc = __builtin_amdgcn_mfma_f32_16x16x32_bf16(a_l, b_h, acc, 0, 0, 0);
  }
  return acc;
}

__global__ __launch_bounds__(256) void mgemm_k(const unsigned short* __restrict__ Ah,
                     const unsigned short* __restrict__ Al,
                     const unsigned short* __restrict__ BTh,
                     const unsigned short* __restrict__ Bl,
                     float* __restrict__ C, int Mr, int KP, int Nc){
  int tilesN = Nc >> 4;
  int wid = ((blockIdx.x*256 + threadIdx.x) >> 6);
  int tm = wid / tilesN, tn = wid - tm*tilesN;
  if (tm*16 >= Mr) return;
  int lane = threadIdx.x & 63;
  int l15 = lane & 15;
  int kb  = (lane >> 4) * 8;
  f32x4 acc = {0.f,0.f,0.f,0.f};
  acc = mfma3(Ah + (size_t)(tm*16 + l15)*KP + kb, Al + (size_t)(tm*16 + l15)*KP + kb,
              BTh + (size_t)(tn*16 + l15)*KP + kb, Bl + (size_t)(tn*16 + l15)*KP + kb,
              KP, acc);
  int r0 = tm*16 + (lane>>4)*4;
  int co = tn*16 + l15;
  #pragma unroll
  for (int r = 0; r < 4; ++r) C[(size_t)(r0+r)*Nc + co] = acc[r];
}

__global__ __launch_bounds__(256) void mgemm2_k(const unsigned short* __restrict__ Ah,
                     const unsigned short* __restrict__ Al,
                     const unsigned short* __restrict__ B1h, const unsigned short* __restrict__ B1l,
                     float* __restrict__ C1, int N1,
                     const unsigned short* __restrict__ B2h, const unsigned short* __restrict__ B2l,
                     float* __restrict__ C2, int N2,
                     int KP){
  int tiles1 = N1 >> 4, tiles2 = N2 >> 4;
  int tilesN = tiles1 + tiles2;
  int wid = ((blockIdx.x*256 + threadIdx.x) >> 6);
  int tm = wid / tilesN, tn = wid - tm*tilesN;
  if (tm >= N_/16) return;
  const unsigned short* bh; const unsigned short* bl;
  float* C; int Nc; int tc;
  if (tn < tiles1){ bh = B1h; bl = B1l; C = C1; Nc = N1; tc = tn; }
  else            { bh = B2h; bl = B2l; C = C2; Nc = N2; tc = tn - tiles1; }
  int lane = threadIdx.x & 63;
  int l15 = lane & 15;
  int kb  = (lane >> 4) * 8;
  f32x4 acc = {0.f,0.f,0.f,0.f};
  acc = mfma3(Ah + (size_t)(tm*16 + l15)*KP + kb, Al + (size_t)(tm*16 + l15)*KP + kb,
              bh + (size_t)(tc*16 + l15)*KP + kb, bl + (size_t)(tc*16 + l15)*KP + kb,
              KP, acc);
  int r0 = tm*16 + (lane>>4)*4;
  int co = tc*16 + l15;
  #pragma unroll
  for (int r = 0; r < 4; ++r) C[(size_t)(r0+r)*Nc + co] = acc[r];
}

template<int O>
__global__ void econtract_k(const float* __restrict__ Y, const int* __restrict__ src,
                            const int* __restrict__ dst, const float* __restrict__ SH,
                            const float* __restrict__ EL, const float* __restrict__ T,
                            float* __restrict__ out, int nE){
  int idx = blockIdx.x*256 + threadIdx.x;
  if (idx >= nE*O) return;
  int e = idx / O, o = idx - e*O;
  const float* sr = SH + (size_t)e*9;
  const float* yr = Y + (size_t)src[e]*(9*O) + o;
  float acc = 0.0f;
  #pragma unroll
  for (int s = 0; s < 9; ++s) acc += sr[s] * yr[s*O];
  float rv = lerp_tab(T, EL[e], O, o);
  atomicAdd(&out[(size_t)dst[e]*O + o], acc * rv);
}

// ---------------- FNO ----------------
__global__ void fc0_k(const float* __restrict__ mf, const float* __restrict__ Wt,
                      const float* __restrict__ bb, float* __restrict__ h){
  int idx = blockIdx.x*256 + threadIdx.x;
  if (idx >= M_*16) return;
  int m = idx >> 4, o = idx & 15;
  int r = m % 8000;
  float fx = (float)(r/400)*0.05f, fy = (float)((r/20)%20)*0.05f, fz = (float)(r%20)*0.05f;
  const float* mfr = mf + (size_t)m*32;
  float acc = bb[o];
  #pragma unroll
  for (int j=0;j<32;++j){
    float v = mfr[j];
    v = v * sigm(fabsf(v));
    acc += v*Wt[j*16+o];
  }
  acc += fx*Wt[32*16+o] + fy*Wt[33*16+o] + fz*Wt[34*16+o];
  h[idx] = acc;
}

__global__ __launch_bounds__(256) void wreorder2_k(const float* __restrict__ wr, const float* __restrict__ wi,
                          float2* __restrict__ W2){
  __shared__ float2 tile[2560];
  int l = blockIdx.y;
  const float* wrl = wr + (size_t)l*1024000;
  const float* wil = wi + (size_t)l*1024000;
  int p = blockIdx.x;
  int ky = p/20, kx = p%20;
  int corner = ((kx>=10)?1:0) + ((ky>=10)?2:0);
  int base2 = corner*256;
  int soff = (kx%10)*100 + (ky%10)*10;
  for (int t = threadIdx.x; t < 2560; t += 256){
    int chunk = t/10, kz = t - chunk*10;
    size_t src = (size_t)(base2 + chunk)*1000 + soff + kz;
    tile[kz*256 + chunk] = make_float2(wrl[src], wil[src]);
  }
  __syncthreads();
  float2* dst = W2 + (size_t)l*1024000 + (size_t)p*2560;
  for (int t = threadIdx.x; t < 2560; t += 256) dst[t] = tile[t];
}

__global__ __launch_bounds__(256) void zyfwd_k(const float* __restrict__ h, float2* __restrict__ cA){
  __shared__ float  pl[20][20][4];
  __shared__ float2 tz[20][10][4];
  __shared__ float2 tw[20];
  int tid = threadIdx.x;
  if (tid < 20){ float a = -6.283185307179586f*tid/20.0f; tw[tid] = make_float2(cosf(a), sinf(a)); }
  int bid = blockIdx.x;
  int b = bid / 80, rem = bid % 80;
  int X = rem >> 2, cg = rem & 3;
  const float* hp = h + (size_t)(b*20+X)*400*16 + cg*4;
  for (int t = tid; t < 400; t += 256) {
    int y = t/20, z = t%20;
    const float4 v = *(const float4*)(hp + (size_t)t*16);
    pl[y][z][0]=v.x; pl[y][z][1]=v.y; pl[y][z][2]=v.z; pl[y][z][3]=v.w;
  }
  __syncthreads();
  for (int t = tid; t < 800; t += 256) {
    int c = t & 3, kz = (t>>2)%10, y = t/40;
    float sr=0.0f, si=0.0f; int j=0;
    for (int z=0; z<20; ++z){
      float v = pl[y][z][c];
      float2 w = tw[j];
      sr += v*w.x; si += v*w.y;
      j += kz; if (j>=20) j-=20;
    }
    tz[y][kz][c] = make_float2(sr,si);
  }
  __syncthreads();
  for (int t = tid; t < 800; t += 256) {
    int c = t & 3, kz = (t>>2)%10, ky = t/40;
    float sr=0.0f, si=0.0f; int j=0;
    for (int y=0; y<20; ++y){
      float2 v = tz[y][kz][c];
      float2 w = tw[j];
      sr += v.x*w.x - v.y*w.y;
      si += v.x*w.y + v.y*w.x;
      j += ky; if (j>=20) j-=20;
    }
    cA[((size_t)((b*20+ky)*10+kz)*20 + X)*16 + cg*4+c] = make_float2(sr,si);
  }
}

__global__ __launch_bounds__(256) void xmix_k(const float2* __restrict__ cA, float2* __restrict__ cB,
                    const float2* __restrict__ W2){
  __shared__ float2 xin[16][20];
  __shared__ float2 Xf[20][16];
  __shared__ float2 Mx[20][16];
  __shared__ float2 twf[20], twi[20];
  int tid = threadIdx.x;
  if (tid < 20){
    float a = -6.283185307179586f*tid/20.0f;
    twf[tid] = make_float2(cosf(a), sinf(a));
    twi[tid] = make_float2(cosf(a), -sinf(a));
  }
  int bid = blockIdx.x;
  int b = bid/200, rem = bid%200;
  int ky = rem/10, kz = rem%10;
  const float2* src = cA + (size_t)((b*20+ky)*10+kz)*320;
  for (int t = tid; t < 320; t += 256){
    int x = t/16, i = t%16;
    xin[i][x] = src[t];
  }
  __syncthreads();
  for (int t = tid; t < 320; t += 256){
    int kx = t/16, i = t%16;
    float sr=0.0f, si=0.0f; int j=0;
    for (int x=0;x<20;++x){
      float2 v = xin[i][x]; float2 w = twf[j];
      sr += v.x*w.x - v.y*w.y; si += v.x*w.y + v.y*w.x;
      j += kx; if (j>=20) j-=20;
    }
    Xf[kx][i] = make_float2(sr,si);
  }
  __syncthreads();
  for (int t = tid; t < 320; t += 256){
    int kx = t/16, o = t%16;
    const float2* wp = W2 + ((size_t)(ky*20+kx)*10 + kz)*256 + o;
    float sr=0.0f, si=0.0f;
    #pragma unroll
    for (int i=0;i<16;++i){
      float2 a = Xf[kx][i];
      float2 w = wp[i*16];
      sr += a.x*w.x - a.y*w.y;
      si += a.x*w.y + a.y*w.x;
    }
    Mx[kx][o] = make_float2(sr,si);
  }
  __syncthreads();
  for (int t = tid; t < 320; t += 256){
    int x = t/16, o = t%16;
    float sr=0.0f, si=0.0f; int j=0;
    for (int kx=0;kx<20;++kx){
      float2 v = Mx[kx][o]; float2 w = twi[j];
      sr += v.x*w.x - v.y*w.y; si += v.x*w.y + v.y*w.x;
      j += x; if (j>=20) j-=20;
    }
    cB[((size_t)((b*20+x)*20+ky)*10+kz)*16 + o] = make_float2(sr,si);
  }
}

__global__ __launch_bounds__(256) void yzinv_k(const float2* __restrict__ cB, float* __restrict__ spec){
  __shared__ float2 ci[20][10][4];
  __shared__ float2 ty[20][10][4];
  __shared__ float2 twi[20];
  int tid = threadIdx.x;
  if (tid < 20){ float a = 6.283185307179586f*tid/20.0f; twi[tid] = make_float2(cosf(a), sinf(a)); }
  int bid = blockIdx.x;
  int b = bid/80, rem = bid%80;
  int X = rem>>2, cg = rem&3;
  const float2* src = cB + (size_t)(b*20+X)*200*16;
  for (int t = tid; t < 800; t += 256){
    int c = t&3, kz = (t>>2)%10, ky = t/40;
    ci[ky][kz][c] = src[(size_t)(ky*10+kz)*16 + cg*4+c];
  }
  __syncthreads();
  for (int t = tid; t < 800; t += 256){
    int c = t&3, kz = (t>>2)%10, y = t/40;
    float sr=0.0f, si=0.0f; int j=0;
    for (int ky=0;ky<20;++ky){
      float2 v = ci[ky][kz][c]; float2 w = twi[j];
      sr += v.x*w.x - v.y*w.y; si += v.x*w.y + v.y*w.x;
      j += y; if (j>=20) j-=20;
    }
    ty[y][kz][c] = make_float2(sr,si);
  }
  __syncthreads();
  float* dst = spec + (size_t)(b*20+X)*400*16 + cg*4;
  for (int t = tid; t < 1600; t += 256){
    int c = t&3, z = (t>>2)%20, y = t/80;
    float acc = ty[y][0][c].x;
    float a2 = 0.0f; int jj = 0;
    for (int kz=1; kz<10; ++kz){
      jj += z; if (jj>=20) jj-=20;
      float2 v = ty[y][kz][c]; float2 w = twi[jj];
      a2 += v.x*w.x - v.y*w.y;
    }
    acc += 2.0f*a2;
    dst[(size_t)(y*20+z)*16 + c] = acc * (1.0f/8000.0f);
  }
}

__global__ __launch_bounds__(256) void ffn3_k(const float* __restrict__ spec, const float* __restrict__ h,
                     const float* __restrict__ pw, const float* __restrict__ ff1,
                     const float* __restrict__ ff2, float* __restrict__ hout){
  __shared__ float spw[256];
  __shared__ float sf1[1024];
  __shared__ float sf2[1024];
  __shared__ float h2s[128][17];
  __shared__ float red[2][128][17];
  int tid = threadIdx.x;
  spw[tid] = pw[tid];
  for (int t = tid; t < 1024; t += 256){ sf1[t]=ff1[t]; sf2[t]=ff2[t]; }
  int rl = tid >> 1, q = tid & 1;
  int m = blockIdx.x*128 + rl;
  const float* hr = h + (size_t)m*16;
  float hl[16];
  #pragma unroll
  for (int i=0;i<16;++i) hl[i] = hr[i];
  __syncthreads();
  const float* sp = spec + (size_t)m*16;
  #pragma unroll
  for (int c=0;c<8;++c){
    int o = q*8+c;
    float acc = sp[o];
    #pragma unroll
    for (int i=0;i<16;++i) acc += hl[i]*spw[i*16+o];
    h2s[rl][o] = geluf(acc);
  }
  __syncthreads();
  float h2l[16];
  #pragma unroll
  for (int i=0;i<16;++i) h2l[i] = h2s[rl][i];
  float part[16] = {};
  for (int kk=0;kk<32;++kk){
    int k = q*32+kk;
    float a0=0.0f, a1=0.0f;
    #pragma unroll
    for (int i=0;i<8;++i){ a0 += h2l[i]*sf1[i*64+k]; a1 += h2l[8+i]*sf1[(8+i)*64+k]; }
    float tk = geluf(a0+a1);
    #pragma unroll
    for (int o=0;o<16;++o) part[o] += tk*sf2[k*16+o];
  }
  #pragma unroll
  for (int o=0;o<16;++o) red[q][rl][o] = part[o];
  __syncthreads();
  #pragma unroll
  for (int c=0;c<8;++c){
    int o = q*8+c;
    hout[(size_t)m*16+o] = h2s[rl][o] + red[0][rl][o] + red[1][rl][o];
  }
}

__global__ __launch_bounds__(256) void fctail3_k(const float* __restrict__ h, const float* __restrict__ fc1,
                        const float* __restrict__ fc2, float* __restrict__ outm){
  __shared__ float s1[2048];
  __shared__ float s2[2048];
  __shared__ float red[2][128][17];
  int tid = threadIdx.x;
  for (int t = tid; t < 2048; t += 256){ s1[t]=fc1[t]; s2[t]=fc2[t]; }
  int rl = tid >> 1, q = tid & 1;
  int m = blockIdx.x*128 + rl;
  const float* hr = h + (size_t)m*16;
  float hl[16];
  #pragma unroll
  for (int i=0;i<16;++i) hl[i] = hr[i];
  __syncthreads();
  float part[16] = {};
  for (int kk=0;kk<64;++kk){
    int k = q*64+kk;
    float a0=0.0f, a1=0.0f;
    #pragma unroll
    for (int i=0;i<8;++i){ a0 += hl[i]*s1[i*128+k]; a1 += hl[8+i]*s1[(8+i)*128+k]; }
    float tk = geluf(a0+a1);
    #pragma unroll
    for (int o=0;o<16;++o) part[o] += tk*s2[k*16+o];
  }
  #pragma unroll
  for (int o=0;o<16;++o) red[q][rl][o] = part[o];
  __syncthreads();
  #pragma unroll
  for (int c=0;c<8;++c){
    int o = q*8+c;
    outm[(size_t)m*16+o] = red[0][rl][o] + red[1][rl][o];
  }
}

// ---------------- m2a + final ----------------
__global__ void m2a_k(const float* __restrict__ mf2, const int* __restrict__ mdst,
                      const int* __restrict__ asrc, const float* __restrict__ sh2,
                      const float* __restrict__ Wt, const float* __restrict__ EL,
                      const float* __restrict__ T, float* __restrict__ af){
  int e = blockIdx.x*256 + threadIdx.x;
  if (e >= E2_) return;
  const float* xr = mf2 + (size_t)mdst[e]*16;
  const float* sr = sh2 + (size_t)e*9;
  float sh[9];
  #pragma unroll
  for (int s=0;s<9;++s) sh[s] = sr[s];
  float acc = 0.0f;
  #pragma unroll
  for (int f=0;f<16;++f) {
    float xv = xr[f];
    float dot = 0.0f;
    #pragma unroll
    for (int s=0;s<9;++s) dot += sh[s]*Wt[f*9+s];
    acc += xv*dot;
  }
  float rv = lerp_tab(T, EL[e], 1, 0);
  atomicAdd(&af[asrc[e]], acc*rv);
}

__global__ void bsum_k(const float* __restrict__ af, const int* __restrict__ batch,
                       float* __restrict__ out){
  int n = blockIdx.x*256 + threadIdx.x;
  if (n >= N_) return;
  atomicAdd(&out[batch[n]], af[n]);
}

} // namespace

extern "C" void kernel_launch(void* const* d_in, const int* in_sizes, int n_in,
                              void* d_out, int out_size, void* d_ws, size_t ws_size,
                              hipStream_t stream) {
  (void)in_sizes; (void)n_in; (void)out_size; (void)ws_size;
  const float* pos   = (const float*)d_in[0];
  const float* cell  = (const float*)d_in[1];
  const int*   an    = (const int*)d_in[2];
  const int*   batch = (const int*)d_in[3];
  const int*   esrc  = (const int*)d_in[4];
  const int*   edst  = (const int*)d_in[5];
  const int*   asrc  = (const int*)d_in[6];
  const int*   mdst  = (const int*)d_in[7];
  const float* emb   = (const float*)d_in[8];
  const float* g0_W  = (const float*)d_in[9];
  const float* g0_Wsc= (const float*)d_in[10];
  const float* g0_m1 = (const float*)d_in[11];
  const float* g0_m2 = (const float*)d_in[12];
  const float* g0_m3 = (const float*)d_in[13];
  const float* g12_W = (const float*)d_in[14];
  const float* g12_Wsc=(const float*)d_in[15];
  const float* g12_m1= (const float*)d_in[16];
  const float* g12_m2= (const float*)d_in[17];
  const float* g12_m3= (const float*)d_in[18];
  const float* a2m_W = (const float*)d_in[19];
  const float* a2m_m1= (const float*)d_in[20];
  const float* a2m_m2= (const float*)d_in[21];
  const float* a2m_m3= (const float*)d_in[22];
  const float* m2a_W = (const float*)d_in[23];
  const float* m2a_m1= (const float*)d_in[24];
  const float* m2a_m2= (const float*)d_in[25];
  const float* m2a_m3= (const float*)d_in[26];
  const float* fc0_W = (const float*)d_in[27];
  const float* fc0_b = (const float*)d_in[28];
  const float* sw_r  = (const float*)d_in[29];
  const float* sw_i  = (const float*)d_in[30];
  const float* pw    = (const float*)d_in[31];
  const float* ff1   = (const float*)d_in[32];
  const float* ff2   = (const float*)d_in[33];
  const float* fc1   = (const float*)d_in[34];
  const float* fc2   = (const float*)d_in[35];
  float* out = (float*)d_out;

  float* Wp = (float*)d_ws;
  size_t off = 0;
  auto alloc = [&](size_t n){ off = (off+3)&~(size_t)3; float* p = Wp + off; off += n; return p; };
  float* meshpos = alloc((size_t)M_*3);
  float* she   = alloc((size_t)E_*9);
  float* ELe   = alloc((size_t)E_);
  float* sh2   = alloc((size_t)E2_*9);
  float* EL2   = alloc((size_t)E2_);
  float* xatom = alloc((size_t)N_*144);
  float* Yg    = alloc((size_t)N_*1296);
  float* mf    = alloc((size_t)M_*32);
  float* hbuf  = alloc((size_t)M_*16);
  float* htmp  = alloc((size_t)M_*16);
  float2* cA   = (float2*)alloc(1024000);
  float2* cB   = (float2*)alloc(1024000);
  float2* W2   = (float2*)alloc((size_t)3*2048000);
  float* af    = alloc((size_t)N_);
  float* Es    = alloc((size_t)NT_*64);
  float* H1g   = alloc((size_t)5*NT_*128);
  float* H2g   = alloc((size_t)5*NT_*128);
  float* T0    = alloc((size_t)NT_*144);
  float* T1    = alloc((size_t)NT_*144);
  float* T2    = alloc((size_t)NT_*144);
  float* T3    = alloc((size_t)NT_*32);
  float* T4    = alloc((size_t)NT_*1);
  unsigned short* Ah  = (unsigned short*)alloc((size_t)N_*160/2);
  unsigned short* Al  = (unsigned short*)alloc((size_t)N_*160/2);
  unsigned short* BTh = (unsigned short*)alloc((size_t)1296*160/2);
  unsigned short* BTl = (unsigned short*)alloc((size_t)1296*160/2);
  unsigned short* BWh = (unsigned short*)alloc((size_t)144*160/2);
  unsigned short* BWl = (unsigned short*)alloc((size_t)144*160/2);

  auto g1 = [](int n){ return dim3((unsigned)((n+255)/256)); };
  auto mg = [](int tiles){ return dim3((unsigned)((tiles+3)/4)); };
  const int TM = N_/16;

  // zero accumulators (single launch)
  zero3_k<<<g1(M_*32), 256, 0, stream>>>(out, af, mf);

  // geometry
  meshpos_k<<<g1(M_), 256, 0, stream>>>(cell, meshpos);
  edge_both_k<<<g1(E_+E2_), 256, 0, stream>>>(pos, meshpos, esrc, edst, asrc, mdst,
                                              she, ELe, sh2, EL2);
  gatherconvA_k<<<g1(N_*32), 256, 0, stream>>>(emb, an, Ah, Al);

  // spectral weight reorder
  wreorder2_k<<<dim3(400,3), 256, 0, stream>>>(sw_r, sw_i, W2);

  // ---- radial tables via 3 batched fp32 GEMMs ----
  {
    es_k<<<g1(NT_*64), 256, 0, stream>>>(Es);
    BG l1, l2, l3;
    const float* m1s[5] = {g0_m1, g12_m1, g12_m1+(size_t)64*128, a2m_m1, m2a_m1};
    const float* m2s[5] = {g0_m2, g12_m2, g12_m2+(size_t)128*128, a2m_m2, m2a_m2};
    const float* m3s[5] = {g0_m3, g12_m3, g12_m3+(size_t)128*144, a2m_m3, m2a_m3};
    float* Ts[5] = {T0, T1, T2, T3, T4};
    int NOs[5] = {144, 144, 144, 32, 1};
    for (int c = 0; c < 5; ++c) {
      l1.A[c] = Es;                      l1.B[c] = m1s[c]; l1.C[c] = H1g + (size_t)c*NT_*128; l1.Nc[c] = 128;
      l2.A[c] = H1g + (size_t)c*NT_*128; l2.B[c] = m2s[c]; l2.C[c] = H2g + (size_t)c*NT_*128; l2.Nc[c] = 128;
      l3.A[c] = H2g + (size_t)c*NT_*128; l3.B[c] = m3s[c]; l3.C[c] = Ts[c];                   l3.Nc[c] = NOs[c];
    }
    l1.K = 64; l2.K = 128; l3.K = 128;
    bgemm_k<1><<<dim3(2, NT_/64, 5), 256, 0, stream>>>(l1);
    bgemm_k<1><<<dim3(2, NT_/64, 5), 256, 0, stream>>>(l2);
    bgemm_k<0><<<dim3(3, NT_/64, 5), 256, 0, stream>>>(l3);
  }

  // ---- g0 (KP=32) ----
  wreshapeT_k<144><<<g1(9*144*32), 256, 0, stream>>>(g0_W, BTh, BTl, 16, 32);
  convT_k<<<g1(144*32), 256, 0, stream>>>(g0_Wsc, BWh, BWl, 16, 144, 32);
  mgemm2_k<<<mg(TM*90), 256, 0, stream>>>(Ah, Al, BTh, BTl, Yg, 1296,
                                          BWh, BWl, xatom, 144, 32);
  econtract_k<144><<<g1(E_*144), 256, 0, stream>>>(Yg, esrc, edst, she, ELe, T0, xatom, E_);

  // ---- g12 x2 (KP=160) ----
  for (int i = 0; i < 2; ++i) {
    normact_bf_k<<<g1(N_*16), 256, 0, stream>>>(xatom, Ah, Al);
    wreshapeT_k<144><<<g1(9*144*160), 256, 0, stream>>>(g12_W + (size_t)i*1296*144, BTh, BTl, 144, 160);
    convT_k<<<g1(144*160), 256, 0, stream>>>(g12_Wsc + (size_t)i*144*144, BWh, BWl, 144, 144, 160);
    mgemm2_k<<<mg(TM*90), 256, 0, stream>>>(Ah, Al, BTh, BTl, Yg, 1296,
                                            BWh, BWl, xatom, 144, 160);
    econtract_k<144><<<g1(E_*144), 256, 0, stream>>>(Yg, esrc, edst, she, ELe, (i==0)?T1:T2, xatom, E_);
  }

  // ---- a2m (KP=160) ----
  convA_k<<<g1(N_*160), 256, 0, stream>>>(xatom, Ah, Al, N_, 144, 160);
  wreshapeT_k<32><<<g1(9*32*160), 256, 0, stream>>>(a2m_W, BTh, BTl, 144, 160);
  mgemm_k<<<mg(TM*18), 256, 0, stream>>>(Ah, Al, BTh, BTl, Yg, N_, 160, 288);
  econtract_k<32><<<g1(E2_*32), 256, 0, stream>>>(Yg, asrc, mdst, sh2, EL2, T3, mf, E2_);

  // ---- FNO ----
  fc0_k<<<g1(M_*16), 256, 0, stream>>>(mf, fc0_W, fc0_b, hbuf);
  for (int l = 0; l < 3; ++l) {
    zyfwd_k<<<dim3(640), 256, 0, stream>>>(hbuf, cA);
    xmix_k<<<dim3(1600), 256, 0, stream>>>(cA, cB, W2 + (size_t)l*1024000);
    yzinv_k<<<dim3(640), 256, 0, stream>>>(cB, htmp);
    ffn3_k<<<dim3(500), 256, 0, stream>>>(htmp, hbuf, pw + (size_t)l*256,
                                          ff1 + (size_t)l*1024, ff2 + (size_t)l*1024, hbuf);
  }
  fctail3_k<<<dim3(500), 256, 0, stream>>>(hbuf, fc1, fc2, htmp);

  // ---- m2a + batch reduce ----
  m2a_k<<<g1(E2_), 256, 0, stream>>>(htmp, mdst, asrc, sh2, m2a_W, EL2, T4, af);
  bsum_k<<<g1(N_), 256, 0, stream>>>(af, batch, out);
}